// Round 1
// 473.335 us; speedup vs baseline: 1.1347x; 1.1347x over previous
//
#include <hip/hip_runtime.h>
#include <hip/hip_fp16.h>
#include <cstdint>
#include <cstdio>

#define N_NODES 10000
#define BATCH   32
#define UNITS   64
#define F_DIM   66            // 2 + 64
#define XROW    2048          // fp8 state-part row bytes (64 f * 32 b)
#define MAXE    128
#define KPAD    96            // MFMA K padded (3 x 32)
#define ASTR    104           // accH row stride in halves (96 + 8 pad)

typedef float v2f __attribute__((ext_vector_type(2)));
typedef float f32x4 __attribute__((ext_vector_type(4)));
typedef _Float16 half8 __attribute__((ext_vector_type(8)));

__device__ __forceinline__ float sigmoidf(float x) {
  return 1.0f / (1.0f + __expf(-x));
}

// ---------------- CSR build ----------------
__global__ __launch_bounds__(256) void hist_k(const int* __restrict__ rows,
                                              int* __restrict__ counts, int E2) {
  int e = blockIdx.x * 256 + threadIdx.x;
  if (e < E2) atomicAdd(&counts[rows[e]], 1);
}

__global__ __launch_bounds__(256) void scan_k(const int* __restrict__ counts,
                                              int* __restrict__ rowptr,
                                              int* __restrict__ wofs, int n) {
  __shared__ int sums[256];
  int t = threadIdx.x;
  int base = t * 40;
  int v[40];
  int run = 0;
#pragma unroll
  for (int i = 0; i < 40; ++i) {
    int idx = base + i;
    int c = (idx < n) ? counts[idx] : 0;
    v[i] = run;
    run += c;
  }
  sums[t] = run;
  __syncthreads();
  for (int off = 1; off < 256; off <<= 1) {
    int x = (t >= off) ? sums[t - off] : 0;
    __syncthreads();
    sums[t] += x;
    __syncthreads();
  }
  int tbase = (t == 0) ? 0 : sums[t - 1];
#pragma unroll
  for (int i = 0; i < 40; ++i) {
    int idx = base + i;
    if (idx < n) { int p = tbase + v[i]; rowptr[idx] = p; wofs[idx] = p; }
  }
  if (t == 255) rowptr[n] = sums[255];
}

__global__ __launch_bounds__(256) void scatter_k(const int* __restrict__ rows,
                                                 const int* __restrict__ cols,
                                                 const float* __restrict__ vals,
                                                 int* __restrict__ wofs,
                                                 int* __restrict__ ccol,
                                                 float* __restrict__ cval, int E2) {
  int e = blockIdx.x * 256 + threadIdx.x;
  if (e < E2) {
    int r = rows[e];
    int p = atomicAdd(&wofs[r], 1);
    ccol[p] = cols[e];
    cval[p] = vals[e];
  }
}

// ---------------- weight prep: fp32 [f][j] -> fp16 [j][k], k padded to 96 ----------------
__global__ __launch_bounds__(256) void prep_w(const float* __restrict__ w1,
                                              const float* __restrict__ w2,
                                              _Float16* __restrict__ w1T,
                                              _Float16* __restrict__ w2T) {
  int i = blockIdx.x * 256 + threadIdx.x;
  if (i < 128 * KPAD) {
    int j = i / KPAD, f = i % KPAD;
    w1T[i] = (f < 66) ? (_Float16)w1[f * 128 + j] : (_Float16)0.0f;
  } else if (i < 128 * KPAD + 64 * KPAD) {
    int k = i - 128 * KPAD;
    int j = k / KPAD, f = k % KPAD;
    w2T[k] = (f < 66) ? (_Float16)w2[f * 64 + j] : (_Float16)0.0f;
  }
}

// ---------------- feature builds ----------------
__device__ __forceinline__ void pack_row_fp8(const float* T, int n, int t,
                                             unsigned char* xcat8) {
  int k0 = t * 8;
  int f8 = k0 >> 5;
  int b0 = k0 & 31;
  const float* Ts = &T[(f8 + 2) * 33 + b0];
  int d0 = __builtin_amdgcn_cvt_pk_fp8_f32(Ts[0], Ts[1], 0, false);
  d0     = __builtin_amdgcn_cvt_pk_fp8_f32(Ts[2], Ts[3], d0, true);
  int d1 = __builtin_amdgcn_cvt_pk_fp8_f32(Ts[4], Ts[5], 0, false);
  d1     = __builtin_amdgcn_cvt_pk_fp8_f32(Ts[6], Ts[7], d1, true);
  *reinterpret_cast<uint2*>(xcat8 + (size_t)n * XROW + k0) = make_uint2(d0, d1);
}

__global__ __launch_bounds__(256) void build_x1(const float* __restrict__ inputs,
                                                const float* __restrict__ state,
                                                unsigned char* __restrict__ xcat8,
                                                __half2* __restrict__ xin) {
  int n = blockIdx.x, t = threadIdx.x;
  __shared__ float T[66 * 33];
  int f = t & 63, bq = t >> 6;
#pragma unroll
  for (int bb = 0; bb < 8; ++bb) {
    int b = bq + bb * 4;
    T[(f + 2) * 33 + b] = state[(size_t)b * 640000 + (size_t)n * 64 + f];
  }
  if (t < 64) {
    int b0 = t & 31, f0 = t >> 5;
    T[f0 * 33 + b0] = inputs[(size_t)b0 * 20000 + (size_t)n * 2 + f0];
  }
  __syncthreads();
  pack_row_fp8(T, n, t, xcat8);
  if (t < 32) {
    int f0 = t >> 4, b = (t & 15) * 2;
    xin[(size_t)n * 32 + t] = __floats2half2_rn(T[f0 * 33 + b], T[f0 * 33 + b + 1]);
  }
}

__global__ __launch_bounds__(256) void build_x2(const float* __restrict__ inputs,
                                                const float* __restrict__ state,
                                                const __half* __restrict__ val,
                                                unsigned char* __restrict__ xcat8) {
  int n = blockIdx.x, t = threadIdx.x;
  __shared__ float T[66 * 33];
  int f = t & 63, bq = t >> 6;
  const __half* vrow = val + ((size_t)(n >> 1)) * 4096 + (size_t)(n & 1) * 64;
#pragma unroll
  for (int bb = 0; bb < 8; ++bb) {
    int b = bq + bb * 4;
    float s = state[(size_t)b * 640000 + (size_t)n * 64 + f];
    float r = __half2float(vrow[(size_t)b * 128 + f]);
    T[(f + 2) * 33 + b] = r * s;
  }
  if (t < 64) {
    int b0 = t & 31, f0 = t >> 5;
    T[f0 * 33 + b0] = inputs[(size_t)b0 * 20000 + (size_t)n * 2 + f0];
  }
  __syncthreads();
  pack_row_fp8(T, n, t, xcat8);
}

// ---------------- yin = M @ X_in ----------------
__global__ __launch_bounds__(256) void yin_k(const int* __restrict__ rowptr,
                                             const int* __restrict__ ccol,
                                             const float* __restrict__ cval,
                                             const __half* __restrict__ xin,
                                             float* __restrict__ yin) {
  int n = blockIdx.x * 32 + (threadIdx.x >> 3);
  int lane = threadIdx.x & 7;
  if (n >= N_NODES) return;
  float acc[8];
#pragma unroll
  for (int i = 0; i < 8; ++i) acc[i] = 0.0f;
  int s = rowptr[n], e = rowptr[n + 1];
  for (int ee = s; ee < e; ++ee) {
    int c = ccol[ee];
    float v = cval[ee];
    uint4 raw = reinterpret_cast<const uint4*>(xin + (size_t)c * 64)[lane];
    const __half2* h = reinterpret_cast<const __half2*>(&raw);
#pragma unroll
    for (int i = 0; i < 4; ++i) {
      float2 x = __half22float2(h[i]);
      acc[2 * i]     += v * x.x;
      acc[2 * i + 1] += v * x.y;
    }
  }
  float4* dst = reinterpret_cast<float4*>(yin + (size_t)n * 64 + lane * 8);
  dst[0] = make_float4(acc[0], acc[1], acc[2], acc[3]);
  dst[1] = make_float4(acc[4], acc[5], acc[6], acc[7]);
}

// Consume one 8B chunk (8 fp8) into 4 packed-f32 accumulators (v_pk_fma_f32).
__device__ __forceinline__ void consume8f8(uint2 u, float v, v2f* acc) {
  v2f p0 = __builtin_amdgcn_cvt_pk_f32_fp8((int)u.x, false);
  v2f p1 = __builtin_amdgcn_cvt_pk_f32_fp8((int)u.x, true);
  v2f p2 = __builtin_amdgcn_cvt_pk_f32_fp8((int)u.y, false);
  v2f p3 = __builtin_amdgcn_cvt_pk_f32_fp8((int)u.y, true);
  v2f vv = {v, v};
  acc[0] += vv * p0;
  acc[1] += vv * p1;
  acc[2] += vv * p2;
  acc[3] += vv * p3;
}

// Shared SpMM body. Result staged to fp16 accH[b][k] (stride ASTR halves):
// k=0,1 from yin (input part), k=2..65 state part, k=66..95 zero-padded for MFMA.
__device__ __forceinline__ void spmm_body(int n, int t,
                                          const int* __restrict__ rowptr,
                                          const int* __restrict__ ccol,
                                          const float* __restrict__ cval,
                                          const unsigned char* __restrict__ xcat8,
                                          const float* __restrict__ yin,
                                          _Float16* accH, int2* eCV) {
  v2f acc[4];
#pragma unroll
  for (int i = 0; i < 4; ++i) acc[i] = (v2f){0.0f, 0.0f};

  const char* xbase = reinterpret_cast<const char*>(xcat8) + (size_t)t * 8;

  int s = rowptr[n], e = rowptr[n + 1];
  for (int cs = s; cs < e; cs += MAXE) {
    int cnt = min(e - cs, MAXE);
    __syncthreads();
    for (int i = t; i < cnt; i += 256) {
      eCV[i] = make_int2(ccol[cs + i], __float_as_int(cval[cs + i]));
    }
    __syncthreads();
    if (cnt > 0) {
      uint2 A, B, C;
      float vA = 0.0f, vB = 0.0f, vC = 0.0f;
      {
        int2 cv = eCV[0];
        A = *reinterpret_cast<const uint2*>(xbase + ((size_t)cv.x << 11));
        vA = __int_as_float(cv.y);
      }
      if (cnt > 1) {
        int2 cv = eCV[1];
        B = *reinterpret_cast<const uint2*>(xbase + ((size_t)cv.x << 11));
        vB = __int_as_float(cv.y);
      }
      if (cnt > 2) {
        int2 cv = eCV[2];
        C = *reinterpret_cast<const uint2*>(xbase + ((size_t)cv.x << 11));
        vC = __int_as_float(cv.y);
      }
      int j = 0;
      for (; j + 3 < cnt; ++j) {
        int2 cv = eCV[j + 3];
        uint2 D = *reinterpret_cast<const uint2*>(xbase + ((size_t)cv.x << 11));
        float vD = __int_as_float(cv.y);
        consume8f8(A, vA, acc);
        A = B; vA = vB; B = C; vB = vC; C = D; vC = vD;
      }
      consume8f8(A, vA, acc);
      if (cnt > 1) consume8f8(B, vB, acc);
      if (cnt > 2) consume8f8(C, vC, acc);
    }
  }

  // ---- stage into fp16 accH[b][k] ----
  // thread t owns k0 = t*8 of the state row: f8 = t>>2, b0 = (t&3)*8, 8 consecutive b.
  {
    int f8 = t >> 2;
    int b0 = (t & 3) * 8;
    float a[8] = {acc[0].x, acc[0].y, acc[1].x, acc[1].y,
                  acc[2].x, acc[2].y, acc[3].x, acc[3].y};
    _Float16* dst = accH + (f8 + 2);
#pragma unroll
    for (int i = 0; i < 8; ++i) {
      dst[(b0 + i) * ASTR] = (_Float16)a[i];
    }
  }
  // input part from yin: k = f (0,1), yin layout k = f*32 + b
  if (t < 64) {
    int f = t >> 5, b = t & 31;
    accH[b * ASTR + f] = (_Float16)yin[(size_t)n * 64 + t];
  }
  // zero pad k = 66..103 (38 halves = 19 dwords per row)
  for (int id = t; id < 32 * 19; id += 256) {
    int b = id / 19, c = id % 19;
    *reinterpret_cast<unsigned int*>(
        reinterpret_cast<char*>(accH) + b * (ASTR * 2) + 132 + c * 4) = 0u;
  }
  __syncthreads();
}

// ---------------- phase 1: SpMM + MFMA GEMM(96->128) + sigmoid -> val fp16 ----------------
__global__ __launch_bounds__(256) void gcn1(const int* __restrict__ rowptr,
                                            const int* __restrict__ ccol,
                                            const float* __restrict__ cval,
                                            const unsigned char* __restrict__ xcat8,
                                            const float* __restrict__ yin,
                                            const _Float16* __restrict__ w1T,
                                            const float* __restrict__ b1,
                                            __half* __restrict__ val) {
  int n = blockIdx.x, t = threadIdx.x;
  __shared__ _Float16 accH[32 * ASTR];              // 6656 B
  __shared__ int2  eCV[MAXE];                        // 1024 B
  __shared__ __align__(16) char regionA[32 * 136 * 2]; // 8704 B (vstage)

  spmm_body(n, t, rowptr, ccol, cval, xcat8, yin, accH, eCV);

  // MFMA: C[32x128] = accH[32x96] x W[96x128]; wave w: mt=w&1, nt=(w>>1)*4+tt
  int wv = t >> 6, l = t & 63;
  int mt = wv & 1, ntb = (wv >> 1) * 4;
  int lr = l & 15, lg = l >> 4;
  const _Float16* aB = accH + (size_t)(mt * 16 + lr) * ASTR + lg * 8;
  half8 afr0 = *reinterpret_cast<const half8*>(aB);
  half8 afr1 = *reinterpret_cast<const half8*>(aB + 32);
  half8 afr2 = *reinterpret_cast<const half8*>(aB + 64);
  _Float16* vstage = reinterpret_cast<_Float16*>(regionA);

#pragma unroll
  for (int tt = 0; tt < 4; ++tt) {
    int j = (ntb + tt) * 16 + lr;
    const _Float16* wB = w1T + (size_t)j * KPAD + lg * 8;
    f32x4 c = {0.0f, 0.0f, 0.0f, 0.0f};
    c = __builtin_amdgcn_mfma_f32_16x16x32_f16(afr0, *reinterpret_cast<const half8*>(wB), c, 0, 0, 0);
    c = __builtin_amdgcn_mfma_f32_16x16x32_f16(afr1, *reinterpret_cast<const half8*>(wB + 32), c, 0, 0, 0);
    c = __builtin_amdgcn_mfma_f32_16x16x32_f16(afr2, *reinterpret_cast<const half8*>(wB + 64), c, 0, 0, 0);
    float bj = b1[j];
#pragma unroll
    for (int i = 0; i < 4; ++i) {
      int b = mt * 16 + lg * 4 + i;
      vstage[b * 136 + j] = (_Float16)sigmoidf(c[i] + bj);
    }
  }
  __syncthreads();

  // vectorized copy out: 16 halves (32B) per thread
  int b = t >> 3, jg = t & 7;
  const uint4* src = reinterpret_cast<const uint4*>(vstage + b * 136 + jg * 16);
  uint4 v0 = src[0];
  uint4 v1 = src[1];
  __half* vb = val + (size_t)n * 4096 + b * 128 + jg * 16;
  *reinterpret_cast<uint4*>(vb) = v0;
  *reinterpret_cast<uint4*>(vb + 8) = v1;
}

// ---------------- phase 2: SpMM + MFMA GEMM(96->64) + relu + gate -> out ----------------
__global__ __launch_bounds__(256) void gcn2(const int* __restrict__ rowptr,
                                            const int* __restrict__ ccol,
                                            const float* __restrict__ cval,
                                            const unsigned char* __restrict__ xcat8,
                                            const float* __restrict__ yin,
                                            const _Float16* __restrict__ w2T,
                                            const float* __restrict__ b2,
                                            const __half* __restrict__ val,
                                            const float* __restrict__ state,
                                            float* __restrict__ out) {
  int n = blockIdx.x, t = threadIdx.x;
  __shared__ _Float16 accH[32 * ASTR];
  __shared__ int2  eCV[MAXE];
  __shared__ __align__(16) char regionA[32 * 68 * 4];  // 8704 B (ostage)

  spmm_body(n, t, rowptr, ccol, cval, xcat8, yin, accH, eCV);

  // MFMA: C[32x64] = accH[32x96] x W[96x64]; wave w: mt=w&1, nt=(w>>1)*2+tt
  int wv = t >> 6, l = t & 63;
  int mt = wv & 1, ntb = (wv >> 1) * 2;
  int lr = l & 15, lg = l >> 4;
  const _Float16* aB = accH + (size_t)(mt * 16 + lr) * ASTR + lg * 8;
  half8 afr0 = *reinterpret_cast<const half8*>(aB);
  half8 afr1 = *reinterpret_cast<const half8*>(aB + 32);
  half8 afr2 = *reinterpret_cast<const half8*>(aB + 64);
  float* ostage = reinterpret_cast<float*>(regionA);  // [32][68]

#pragma unroll
  for (int tt = 0; tt < 2; ++tt) {
    int j = (ntb + tt) * 16 + lr;
    const _Float16* wB = w2T + (size_t)j * KPAD + lg * 8;
    f32x4 c = {0.0f, 0.0f, 0.0f, 0.0f};
    c = __builtin_amdgcn_mfma_f32_16x16x32_f16(afr0, *reinterpret_cast<const half8*>(wB), c, 0, 0, 0);
    c = __builtin_amdgcn_mfma_f32_16x16x32_f16(afr1, *reinterpret_cast<const half8*>(wB + 32), c, 0, 0, 0);
    c = __builtin_amdgcn_mfma_f32_16x16x32_f16(afr2, *reinterpret_cast<const half8*>(wB + 64), c, 0, 0, 0);
    float bj = b2[j];
#pragma unroll
    for (int i = 0; i < 4; ++i) {
      int b = mt * 16 + lg * 4 + i;
      ostage[b * 68 + j] = fmaxf(c[i] + bj, 0.0f);  // relu(c) staged
    }
  }
  __syncthreads();

  // gate: new_h = u*state + (1-u)*c
  int bg = t >> 4, jg = t & 15;
  int n2 = n >> 1, no = n & 1;
  const __half* up = val + ((size_t)(5000 + n2)) * 4096 + (size_t)no * 64 + jg * 4;
#pragma unroll
  for (int i = 0; i < 2; ++i) {
    int b = bg * 2 + i;
    size_t idx = (size_t)b * 640000 + (size_t)n * 64 + jg * 4;
    float4 sv = *reinterpret_cast<const float4*>(state + idx);
    float4 cc = *reinterpret_cast<const float4*>(ostage + b * 68 + jg * 4);
    union { uint2 u; __half2 h[2]; } pk;
    pk.u = *reinterpret_cast<const uint2*>(up + (size_t)b * 128);
    float2 u01 = __half22float2(pk.h[0]);
    float2 u23 = __half22float2(pk.h[1]);
    float4 h;
    h.x = u01.x * sv.x + (1.0f - u01.x) * cc.x;
    h.y = u01.y * sv.y + (1.0f - u01.y) * cc.y;
    h.z = u23.x * sv.z + (1.0f - u23.x) * cc.z;
    h.w = u23.y * sv.w + (1.0f - u23.y) * cc.w;
    *reinterpret_cast<float4*>(out + idx) = h;
  }
}

// ---------------- host ----------------
static inline size_t alignup(size_t x) { return (x + 255) & ~(size_t)255; }

extern "C" void kernel_launch(void* const* d_in, const int* in_sizes, int n_in,
                              void* d_out, int out_size, void* d_ws, size_t ws_size,
                              hipStream_t stream) {
  const float* inputs = (const float*)d_in[0];
  const float* state  = (const float*)d_in[1];
  const int*   m_rows = (const int*)d_in[2];
  const int*   m_cols = (const int*)d_in[3];
  const float* m_vals = (const float*)d_in[4];
  const float* w1     = (const float*)d_in[5];
  const float* b1     = (const float*)d_in[6];
  const float* w2     = (const float*)d_in[7];
  const float* b2     = (const float*)d_in[8];
  float* out = (float*)d_out;

  const int N  = N_NODES;
  const int E2 = in_sizes[2];

  char* ws = (char*)d_ws;
  size_t off = 0;
  int* counts = (int*)(ws + off); off = alignup(off + (size_t)N * 4);
  int* rowptr = (int*)(ws + off); off = alignup(off + (size_t)(N + 1) * 4);
  int* wofs   = (int*)(ws + off); off = alignup(off + (size_t)N * 4);
  int* ccol   = (int*)(ws + off); off = alignup(off + (size_t)E2 * 4);
  float* cval = (float*)(ws + off); off = alignup(off + (size_t)E2 * 4);
  unsigned char* xcat8 = (unsigned char*)(ws + off); off = alignup(off + (size_t)N * XROW);
  __half* val = (__half*)(ws + off); off = alignup(off + (size_t)N * 4096 * 2);
  float* yin  = (float*)(ws + off); off = alignup(off + (size_t)N * 64 * 4);
  __half* xin = (__half*)(ws + off); off = alignup(off + (size_t)N * 64 * 2);
  _Float16* w1T = (_Float16*)(ws + off); off = alignup(off + (size_t)128 * KPAD * 2);
  _Float16* w2T = (_Float16*)(ws + off); off = alignup(off + (size_t)64 * KPAD * 2);
  if (off > ws_size) { return; }

  hipMemsetAsync(counts, 0, (size_t)N * 4, stream);

  int eb = (E2 + 255) / 256;
  int wb = (128 * KPAD + 64 * KPAD + 255) / 256;
  hipLaunchKernelGGL(hist_k,    dim3(eb), dim3(256), 0, stream, m_rows, counts, E2);
  hipLaunchKernelGGL(scan_k,    dim3(1),  dim3(256), 0, stream, counts, rowptr, wofs, N);
  hipLaunchKernelGGL(scatter_k, dim3(eb), dim3(256), 0, stream, m_rows, m_cols, m_vals,
                     wofs, ccol, cval, E2);
  hipLaunchKernelGGL(prep_w,    dim3(wb), dim3(256), 0, stream, w1, w2, w1T, w2T);
  hipLaunchKernelGGL(build_x1,  dim3(N),  dim3(256), 0, stream, inputs, state, xcat8,
                     (__half2*)xin);
  hipLaunchKernelGGL(yin_k,     dim3((N + 31) / 32), dim3(256), 0, stream,
                     rowptr, ccol, cval, xin, yin);
  hipLaunchKernelGGL(gcn1,      dim3(N),  dim3(256), 0, stream, rowptr, ccol, cval,
                     xcat8, yin, w1T, b1, val);
  hipLaunchKernelGGL(build_x2,  dim3(N),  dim3(256), 0, stream, inputs, state, val, xcat8);
  hipLaunchKernelGGL(gcn2,      dim3(N),  dim3(256), 0, stream, rowptr, ccol, cval,
                     xcat8, yin, w2T, b2, val, state, out);
}

// Round 2
// 452.087 us; speedup vs baseline: 1.1880x; 1.0470x over previous
//
#include <hip/hip_runtime.h>
#include <hip/hip_fp16.h>
#include <cstdint>
#include <cstdio>

#define N_NODES 10000
#define BATCH   32
#define UNITS   64
#define F_DIM   66            // 2 + 64
#define XROW    2048          // fp8 state-part row bytes (64 f * 32 b)
#define MAXE    128
#define KPAD    96            // MFMA K padded (3 x 32)
#define ASTR    104           // accH row stride in halves (96 + 8 pad)

typedef float v2f __attribute__((ext_vector_type(2)));
typedef float f32x4 __attribute__((ext_vector_type(4)));
typedef _Float16 half8 __attribute__((ext_vector_type(8)));

__device__ __forceinline__ float sigmoidf(float x) {
  return 1.0f / (1.0f + __expf(-x));
}

// ---------------- CSR build ----------------
__global__ __launch_bounds__(256) void hist_k(const int* __restrict__ rows,
                                              int* __restrict__ counts, int E2) {
  int e = blockIdx.x * 256 + threadIdx.x;
  if (e < E2) atomicAdd(&counts[rows[e]], 1);
}

// Single block; counts staged through LDS with coalesced int4 loads.
__global__ __launch_bounds__(256) void scan_k(const int* __restrict__ counts,
                                              int* __restrict__ rowptr,
                                              int* __restrict__ wofs, int n) {
  __shared__ int lbuf[10240];
  __shared__ int sums[256];
  int t = threadIdx.x;
  for (int i = t; i < N_NODES / 4; i += 256)
    reinterpret_cast<int4*>(lbuf)[i] = reinterpret_cast<const int4*>(counts)[i];
  for (int i = N_NODES + t; i < 10240; i += 256) lbuf[i] = 0;
  __syncthreads();
  int base = t * 40;
  int v[40];
  int run = 0;
#pragma unroll
  for (int i = 0; i < 40; ++i) { v[i] = run; run += lbuf[base + i]; }
  sums[t] = run;
  __syncthreads();
  for (int off = 1; off < 256; off <<= 1) {
    int x = (t >= off) ? sums[t - off] : 0;
    __syncthreads();
    sums[t] += x;
    __syncthreads();
  }
  int tbase = (t == 0) ? 0 : sums[t - 1];
#pragma unroll
  for (int i = 0; i < 40; ++i) lbuf[base + i] = tbase + v[i];
  __syncthreads();
  for (int i = t; i < N_NODES / 4; i += 256) {
    int4 w = reinterpret_cast<int4*>(lbuf)[i];
    reinterpret_cast<int4*>(rowptr)[i] = w;
    reinterpret_cast<int4*>(wofs)[i] = w;
  }
  if (t == 255) rowptr[N_NODES] = sums[255];
}

// ccol stores PRE-SHIFTED byte offsets (col * 2048).
__global__ __launch_bounds__(256) void scatter_k(const int* __restrict__ rows,
                                                 const int* __restrict__ cols,
                                                 const float* __restrict__ vals,
                                                 int* __restrict__ wofs,
                                                 int* __restrict__ ccol,
                                                 float* __restrict__ cval, int E2) {
  int e = blockIdx.x * 256 + threadIdx.x;
  if (e < E2) {
    int r = rows[e];
    int p = atomicAdd(&wofs[r], 1);
    ccol[p] = cols[e] << 11;
    cval[p] = vals[e];
  }
}

// ---------------- weight prep: fp32 [f][j] -> fp16 [j][k], k padded to 96 ----------------
__global__ __launch_bounds__(256) void prep_w(const float* __restrict__ w1,
                                              const float* __restrict__ w2,
                                              _Float16* __restrict__ w1T,
                                              _Float16* __restrict__ w2T) {
  int i = blockIdx.x * 256 + threadIdx.x;
  if (i < 128 * KPAD) {
    int j = i / KPAD, f = i % KPAD;
    w1T[i] = (f < 66) ? (_Float16)w1[f * 128 + j] : (_Float16)0.0f;
  } else if (i < 128 * KPAD + 64 * KPAD) {
    int k = i - 128 * KPAD;
    int j = k / KPAD, f = k % KPAD;
    w2T[k] = (f < 66) ? (_Float16)w2[f * 64 + j] : (_Float16)0.0f;
  }
}

// ---------------- feature build (phase 1 only; phase-2 build fused into gcn1) ----------------
__device__ __forceinline__ void pack_row_fp8(const float* T, int n, int t,
                                             unsigned char* xcat8) {
  int k0 = t * 8;
  int f8 = k0 >> 5;
  int b0 = k0 & 31;
  const float* Ts = &T[(f8 + 2) * 33 + b0];
  int d0 = __builtin_amdgcn_cvt_pk_fp8_f32(Ts[0], Ts[1], 0, false);
  d0     = __builtin_amdgcn_cvt_pk_fp8_f32(Ts[2], Ts[3], d0, true);
  int d1 = __builtin_amdgcn_cvt_pk_fp8_f32(Ts[4], Ts[5], 0, false);
  d1     = __builtin_amdgcn_cvt_pk_fp8_f32(Ts[6], Ts[7], d1, true);
  *reinterpret_cast<uint2*>(xcat8 + (size_t)n * XROW + k0) = make_uint2(d0, d1);
}

__global__ __launch_bounds__(256) void build_x1(const float* __restrict__ inputs,
                                                const float* __restrict__ state,
                                                unsigned char* __restrict__ xcat8,
                                                __half2* __restrict__ xin) {
  int n = blockIdx.x, t = threadIdx.x;
  __shared__ float T[66 * 33];
  int f = t & 63, bq = t >> 6;
#pragma unroll
  for (int bb = 0; bb < 8; ++bb) {
    int b = bq + bb * 4;
    T[(f + 2) * 33 + b] = state[(size_t)b * 640000 + (size_t)n * 64 + f];
  }
  if (t < 64) {
    int b0 = t & 31, f0 = t >> 5;
    T[f0 * 33 + b0] = inputs[(size_t)b0 * 20000 + (size_t)n * 2 + f0];
  }
  __syncthreads();
  pack_row_fp8(T, n, t, xcat8);
  if (t < 32) {
    int f0 = t >> 4, b = (t & 15) * 2;
    xin[(size_t)n * 32 + t] = __floats2half2_rn(T[f0 * 33 + b], T[f0 * 33 + b + 1]);
  }
}

// ---------------- yin = M @ X_in ----------------
__global__ __launch_bounds__(256) void yin_k(const int* __restrict__ rowptr,
                                             const int* __restrict__ ccol,
                                             const float* __restrict__ cval,
                                             const __half* __restrict__ xin,
                                             float* __restrict__ yin) {
  int n = blockIdx.x * 32 + (threadIdx.x >> 3);
  int lane = threadIdx.x & 7;
  if (n >= N_NODES) return;
  float acc[8];
#pragma unroll
  for (int i = 0; i < 8; ++i) acc[i] = 0.0f;
  int s = rowptr[n], e = rowptr[n + 1];
  for (int ee = s; ee < e; ++ee) {
    int c = ccol[ee];                 // byte offset col*2048
    float v = cval[ee];
    const char* p = reinterpret_cast<const char*>(xin) + (size_t)(unsigned)(c >> 4);
    uint4 raw = reinterpret_cast<const uint4*>(p)[lane];
    const __half2* h = reinterpret_cast<const __half2*>(&raw);
#pragma unroll
    for (int i = 0; i < 4; ++i) {
      float2 x = __half22float2(h[i]);
      acc[2 * i]     += v * x.x;
      acc[2 * i + 1] += v * x.y;
    }
  }
  float4* dst = reinterpret_cast<float4*>(yin + (size_t)n * 64 + lane * 8);
  dst[0] = make_float4(acc[0], acc[1], acc[2], acc[3]);
  dst[1] = make_float4(acc[4], acc[5], acc[6], acc[7]);
}

// Consume one 8B chunk (8 fp8) into 4 packed-f32 accumulators (v_pk_fma_f32).
__device__ __forceinline__ void consume8f8(uint2 u, float v, v2f* acc) {
  v2f p0 = __builtin_amdgcn_cvt_pk_f32_fp8((int)u.x, false);
  v2f p1 = __builtin_amdgcn_cvt_pk_f32_fp8((int)u.x, true);
  v2f p2 = __builtin_amdgcn_cvt_pk_f32_fp8((int)u.y, false);
  v2f p3 = __builtin_amdgcn_cvt_pk_f32_fp8((int)u.y, true);
  v2f vv = {v, v};
  acc[0] += vv * p0;
  acc[1] += vv * p1;
  acc[2] += vv * p2;
  acc[3] += vv * p3;
}

#define LDE(RR, VV, IDX) do { int2 cv = eCV[(IDX)]; \
  RR = *reinterpret_cast<const uint2*>(xbase + (size_t)(unsigned)cv.x); \
  VV = __int_as_float(cv.y); } while (0)

// Shared SpMM body, 7-deep gather pipeline. Result staged to fp16 accH[b][k]:
// k=0,1 from yin (input part), k=2..65 state part, k=66..95 zero-padded for MFMA.
__device__ __forceinline__ void spmm_body(int n, int t,
                                          const int* __restrict__ rowptr,
                                          const int* __restrict__ ccol,
                                          const float* __restrict__ cval,
                                          const unsigned char* __restrict__ xcat8,
                                          const float* __restrict__ yin,
                                          _Float16* accH, int2* eCV) {
  v2f acc[4];
#pragma unroll
  for (int i = 0; i < 4; ++i) acc[i] = (v2f){0.0f, 0.0f};

  const char* xbase = reinterpret_cast<const char*>(xcat8) + (size_t)t * 8;

  int s = rowptr[n], e = rowptr[n + 1];
  for (int cs = s; cs < e; cs += MAXE) {
    int cnt = min(e - cs, MAXE);
    __syncthreads();
    for (int i = t; i < cnt; i += 256) {
      eCV[i] = make_int2(ccol[cs + i], __float_as_int(cval[cs + i]));
    }
    __syncthreads();

    uint2 r0 = {0,0}, r1 = {0,0}, r2 = {0,0}, r3 = {0,0}, r4 = {0,0}, r5 = {0,0}, r6 = {0,0};
    float v0 = 0, v1 = 0, v2 = 0, v3 = 0, v4 = 0, v5 = 0, v6 = 0;
    if (cnt > 0) LDE(r0, v0, 0);
    if (cnt > 1) LDE(r1, v1, 1);
    if (cnt > 2) LDE(r2, v2, 2);
    if (cnt > 3) LDE(r3, v3, 3);
    if (cnt > 4) LDE(r4, v4, 4);
    if (cnt > 5) LDE(r5, v5, 5);
    if (cnt > 6) LDE(r6, v6, 6);
    int j = 0;
    for (; j + 13 < cnt; j += 7) {          // steady: no register rotation
      consume8f8(r0, v0, acc); LDE(r0, v0, j + 7);
      consume8f8(r1, v1, acc); LDE(r1, v1, j + 8);
      consume8f8(r2, v2, acc); LDE(r2, v2, j + 9);
      consume8f8(r3, v3, acc); LDE(r3, v3, j + 10);
      consume8f8(r4, v4, acc); LDE(r4, v4, j + 11);
      consume8f8(r5, v5, acc); LDE(r5, v5, j + 12);
      consume8f8(r6, v6, acc); LDE(r6, v6, j + 13);
    }
    for (; j + 7 < cnt; ++j) {              // <=6 rotating iterations
      consume8f8(r0, v0, acc);
      uint2 nr; float nv;
      LDE(nr, nv, j + 7);
      r0 = r1; v0 = v1; r1 = r2; v1 = v2; r2 = r3; v2 = v3;
      r3 = r4; v3 = v4; r4 = r5; v4 = v5; r5 = r6; v5 = v6;
      r6 = nr; v6 = nv;
    }
    if (j + 0 < cnt) consume8f8(r0, v0, acc);
    if (j + 1 < cnt) consume8f8(r1, v1, acc);
    if (j + 2 < cnt) consume8f8(r2, v2, acc);
    if (j + 3 < cnt) consume8f8(r3, v3, acc);
    if (j + 4 < cnt) consume8f8(r4, v4, acc);
    if (j + 5 < cnt) consume8f8(r5, v5, acc);
    if (j + 6 < cnt) consume8f8(r6, v6, acc);
  }

  // ---- stage into fp16 accH[b][k] ----
  {
    int f8 = t >> 2;
    int b0 = (t & 3) * 8;
    float a[8] = {acc[0].x, acc[0].y, acc[1].x, acc[1].y,
                  acc[2].x, acc[2].y, acc[3].x, acc[3].y};
    _Float16* dst = accH + (f8 + 2);
#pragma unroll
    for (int i = 0; i < 8; ++i) {
      dst[(b0 + i) * ASTR] = (_Float16)a[i];
    }
  }
  if (t < 64) {
    int f = t >> 5, b = t & 31;
    accH[b * ASTR + f] = (_Float16)yin[(size_t)n * 64 + t];
  }
  for (int id = t; id < 32 * 19; id += 256) {
    int b = id / 19, c = id % 19;
    *reinterpret_cast<unsigned int*>(
        reinterpret_cast<char*>(accH) + b * (ASTR * 2) + 132 + c * 4) = 0u;
  }
  __syncthreads();
}

// ---------------- phase 1: SpMM + MFMA GEMM + sigmoid ----------------
// n < 5000 : outputs are r-gates of nodes 2n,2n+1 -> emit fp8 x2 rows (r*state) directly.
// n >= 5000: outputs are u-gates -> write fp16 val_u rows (node index n-5000).
__global__ __launch_bounds__(256) void gcn1(const int* __restrict__ rowptr,
                                            const int* __restrict__ ccol,
                                            const float* __restrict__ cval,
                                            const unsigned char* __restrict__ xcat8,
                                            const float* __restrict__ yin,
                                            const _Float16* __restrict__ w1T,
                                            const float* __restrict__ b1,
                                            const float* __restrict__ state,
                                            unsigned char* __restrict__ xcat2,
                                            __half* __restrict__ valu) {
  int n = blockIdx.x, t = threadIdx.x;
  __shared__ _Float16 accH[32 * ASTR];                 // 6656 B
  __shared__ int2  eCV[MAXE];                          // 1024 B
  __shared__ __align__(16) char regionA[32 * 136 * 2]; // 8704 B (vstage)

  spmm_body(n, t, rowptr, ccol, cval, xcat8, yin, accH, eCV);

  int wv = t >> 6, l = t & 63;
  int mt = wv & 1, ntb = (wv >> 1) * 4;
  int lr = l & 15, lg = l >> 4;
  const _Float16* aB = accH + (size_t)(mt * 16 + lr) * ASTR + lg * 8;
  half8 afr0 = *reinterpret_cast<const half8*>(aB);
  half8 afr1 = *reinterpret_cast<const half8*>(aB + 32);
  half8 afr2 = *reinterpret_cast<const half8*>(aB + 64);
  _Float16* vstage = reinterpret_cast<_Float16*>(regionA);

#pragma unroll
  for (int tt = 0; tt < 4; ++tt) {
    int j = (ntb + tt) * 16 + lr;
    const _Float16* wB = w1T + (size_t)j * KPAD + lg * 8;
    f32x4 c = {0.0f, 0.0f, 0.0f, 0.0f};
    c = __builtin_amdgcn_mfma_f32_16x16x32_f16(afr0, *reinterpret_cast<const half8*>(wB), c, 0, 0, 0);
    c = __builtin_amdgcn_mfma_f32_16x16x32_f16(afr1, *reinterpret_cast<const half8*>(wB + 32), c, 0, 0, 0);
    c = __builtin_amdgcn_mfma_f32_16x16x32_f16(afr2, *reinterpret_cast<const half8*>(wB + 64), c, 0, 0, 0);
    float bj = b1[j];
#pragma unroll
    for (int i = 0; i < 4; ++i) {
      int b = mt * 16 + lg * 4 + i;
      vstage[b * 136 + j] = (_Float16)sigmoidf(c[i] + bj);
    }
  }
  __syncthreads();

  if (n < 5000) {
    // r-path: xcat2[nn][f*32 + b] = fp8( r(nn,b,f) * state[b][nn][f] ), nn = 2n + (t>>7)
    int nn_i = t >> 7, rem = t & 127;
    int f = rem >> 1, b0 = (rem & 1) * 16;
    int nn = n * 2 + nn_i;
    int jj = nn_i * 64 + f;
    const float* sp = state + (size_t)b0 * 640000 + (size_t)nn * 64 + f;
    const _Float16* vp = vstage + b0 * 136 + jj;
    unsigned int d[4];
#pragma unroll
    for (int q = 0; q < 4; ++q) {
      float x0 = (float)vp[(4 * q + 0) * 136] * sp[(size_t)(4 * q + 0) * 640000];
      float x1 = (float)vp[(4 * q + 1) * 136] * sp[(size_t)(4 * q + 1) * 640000];
      float x2 = (float)vp[(4 * q + 2) * 136] * sp[(size_t)(4 * q + 2) * 640000];
      float x3 = (float)vp[(4 * q + 3) * 136] * sp[(size_t)(4 * q + 3) * 640000];
      int dd = __builtin_amdgcn_cvt_pk_fp8_f32(x0, x1, 0, false);
      dd     = __builtin_amdgcn_cvt_pk_fp8_f32(x2, x3, dd, true);
      d[q] = (unsigned)dd;
    }
    *reinterpret_cast<uint4*>(xcat2 + (size_t)nn * XROW + f * 32 + b0) =
        make_uint4(d[0], d[1], d[2], d[3]);
  } else {
    // u-path: vectorized copy to valu (node index n-5000)
    int b = t >> 3, jg = t & 7;
    const uint4* src = reinterpret_cast<const uint4*>(vstage + b * 136 + jg * 16);
    uint4 q0 = src[0];
    uint4 q1 = src[1];
    __half* vb = valu + (size_t)(n - 5000) * 4096 + b * 128 + jg * 16;
    *reinterpret_cast<uint4*>(vb) = q0;
    *reinterpret_cast<uint4*>(vb + 8) = q1;
  }
}

// ---------------- phase 2: SpMM + MFMA GEMM(96->64) + relu + gate -> out ----------------
__global__ __launch_bounds__(256) void gcn2(const int* __restrict__ rowptr,
                                            const int* __restrict__ ccol,
                                            const float* __restrict__ cval,
                                            const unsigned char* __restrict__ xcat2,
                                            const float* __restrict__ yin,
                                            const _Float16* __restrict__ w2T,
                                            const float* __restrict__ b2,
                                            const __half* __restrict__ valu,
                                            const float* __restrict__ state,
                                            float* __restrict__ out) {
  int n = blockIdx.x, t = threadIdx.x;
  __shared__ _Float16 accH[32 * ASTR];
  __shared__ int2  eCV[MAXE];
  __shared__ __align__(16) char regionA[32 * 68 * 4];  // ostage

  spmm_body(n, t, rowptr, ccol, cval, xcat2, yin, accH, eCV);

  int wv = t >> 6, l = t & 63;
  int mt = wv & 1, ntb = (wv >> 1) * 2;
  int lr = l & 15, lg = l >> 4;
  const _Float16* aB = accH + (size_t)(mt * 16 + lr) * ASTR + lg * 8;
  half8 afr0 = *reinterpret_cast<const half8*>(aB);
  half8 afr1 = *reinterpret_cast<const half8*>(aB + 32);
  half8 afr2 = *reinterpret_cast<const half8*>(aB + 64);
  float* ostage = reinterpret_cast<float*>(regionA);   // [32][68]

#pragma unroll
  for (int tt = 0; tt < 2; ++tt) {
    int j = (ntb + tt) * 16 + lr;
    const _Float16* wB = w2T + (size_t)j * KPAD + lg * 8;
    f32x4 c = {0.0f, 0.0f, 0.0f, 0.0f};
    c = __builtin_amdgcn_mfma_f32_16x16x32_f16(afr0, *reinterpret_cast<const half8*>(wB), c, 0, 0, 0);
    c = __builtin_amdgcn_mfma_f32_16x16x32_f16(afr1, *reinterpret_cast<const half8*>(wB + 32), c, 0, 0, 0);
    c = __builtin_amdgcn_mfma_f32_16x16x32_f16(afr2, *reinterpret_cast<const half8*>(wB + 64), c, 0, 0, 0);
    float bj = b2[j];
#pragma unroll
    for (int i = 0; i < 4; ++i) {
      int b = mt * 16 + lg * 4 + i;
      ostage[b * 68 + j] = fmaxf(c[i] + bj, 0.0f);
    }
  }
  __syncthreads();

  int bg = t >> 4, jg = t & 15;
  int n2 = n >> 1, no = n & 1;
  const __half* up = valu + (size_t)n2 * 4096 + (size_t)no * 64 + jg * 4;
#pragma unroll
  for (int i = 0; i < 2; ++i) {
    int b = bg * 2 + i;
    size_t idx = (size_t)b * 640000 + (size_t)n * 64 + jg * 4;
    float4 sv = *reinterpret_cast<const float4*>(state + idx);
    float4 cc = *reinterpret_cast<const float4*>(ostage + b * 68 + jg * 4);
    union { uint2 u; __half2 h[2]; } pk;
    pk.u = *reinterpret_cast<const uint2*>(up + (size_t)b * 128);
    float2 u01 = __half22float2(pk.h[0]);
    float2 u23 = __half22float2(pk.h[1]);
    float4 h;
    h.x = u01.x * sv.x + (1.0f - u01.x) * cc.x;
    h.y = u01.y * sv.y + (1.0f - u01.y) * cc.y;
    h.z = u23.x * sv.z + (1.0f - u23.x) * cc.z;
    h.w = u23.y * sv.w + (1.0f - u23.y) * cc.w;
    *reinterpret_cast<float4*>(out + idx) = h;
  }
}

// ---------------- host ----------------
static inline size_t alignup(size_t x) { return (x + 255) & ~(size_t)255; }

extern "C" void kernel_launch(void* const* d_in, const int* in_sizes, int n_in,
                              void* d_out, int out_size, void* d_ws, size_t ws_size,
                              hipStream_t stream) {
  const float* inputs = (const float*)d_in[0];
  const float* state  = (const float*)d_in[1];
  const int*   m_rows = (const int*)d_in[2];
  const int*   m_cols = (const int*)d_in[3];
  const float* m_vals = (const float*)d_in[4];
  const float* w1     = (const float*)d_in[5];
  const float* b1     = (const float*)d_in[6];
  const float* w2     = (const float*)d_in[7];
  const float* b2     = (const float*)d_in[8];
  float* out = (float*)d_out;

  const int N  = N_NODES;
  const int E2 = in_sizes[2];

  char* ws = (char*)d_ws;
  size_t off = 0;
  int* counts = (int*)(ws + off); off = alignup(off + (size_t)N * 4);
  int* rowptr = (int*)(ws + off); off = alignup(off + (size_t)(N + 1) * 4);
  int* wofs   = (int*)(ws + off); off = alignup(off + (size_t)N * 4);
  int* ccol   = (int*)(ws + off); off = alignup(off + (size_t)E2 * 4);
  float* cval = (float*)(ws + off); off = alignup(off + (size_t)E2 * 4);
  unsigned char* xcat8 = (unsigned char*)(ws + off); off = alignup(off + (size_t)N * XROW);
  unsigned char* xcat2 = (unsigned char*)(ws + off); off = alignup(off + (size_t)N * XROW);
  __half* valu = (__half*)(ws + off); off = alignup(off + (size_t)5000 * 4096 * 2);
  float* yin  = (float*)(ws + off); off = alignup(off + (size_t)N * 64 * 4);
  __half* xin = (__half*)(ws + off); off = alignup(off + (size_t)N * 64 * 2);
  _Float16* w1T = (_Float16*)(ws + off); off = alignup(off + (size_t)128 * KPAD * 2);
  _Float16* w2T = (_Float16*)(ws + off); off = alignup(off + (size_t)64 * KPAD * 2);
  if (off > ws_size) { return; }

  hipMemsetAsync(counts, 0, (size_t)N * 4, stream);

  int eb = (E2 + 255) / 256;
  int wb = (128 * KPAD + 64 * KPAD + 255) / 256;
  hipLaunchKernelGGL(hist_k,    dim3(eb), dim3(256), 0, stream, m_rows, counts, E2);
  hipLaunchKernelGGL(scan_k,    dim3(1),  dim3(256), 0, stream, counts, rowptr, wofs, N);
  hipLaunchKernelGGL(scatter_k, dim3(eb), dim3(256), 0, stream, m_rows, m_cols, m_vals,
                     wofs, ccol, cval, E2);
  hipLaunchKernelGGL(prep_w,    dim3(wb), dim3(256), 0, stream, w1, w2, w1T, w2T);
  hipLaunchKernelGGL(build_x1,  dim3(N),  dim3(256), 0, stream, inputs, state, xcat8,
                     (__half2*)xin);
  hipLaunchKernelGGL(yin_k,     dim3((N + 31) / 32), dim3(256), 0, stream,
                     rowptr, ccol, cval, xin, yin);
  hipLaunchKernelGGL(gcn1,      dim3(N),  dim3(256), 0, stream, rowptr, ccol, cval,
                     xcat8, yin, w1T, b1, state, xcat2, valu);
  hipLaunchKernelGGL(gcn2,      dim3(N),  dim3(256), 0, stream, rowptr, ccol, cval,
                     xcat2, yin, w2T, b2, valu, state, out);
}

// Round 3
// 438.904 us; speedup vs baseline: 1.2237x; 1.0300x over previous
//
#include <hip/hip_runtime.h>
#include <hip/hip_fp16.h>
#include <cstdint>
#include <cstdio>

#define N_NODES 10000
#define BATCH   32
#define UNITS   64
#define F_DIM   66            // 2 + 64
#define XROW    2048          // fp8 state-part row bytes (64 f * 32 b)
#define KPAD    96            // MFMA K padded (3 x 32)
#define ASTR    104           // accH row stride in halves (96 + 8 pad)

typedef float v2f __attribute__((ext_vector_type(2)));
typedef float f32x4 __attribute__((ext_vector_type(4)));
typedef _Float16 half8 __attribute__((ext_vector_type(8)));

__device__ __forceinline__ float sigmoidf(float x) {
  return 1.0f / (1.0f + __expf(-x));
}

// ---------------- CSR build (+ weight prep folded in) ----------------
__global__ __launch_bounds__(256) void hist_k(const int* __restrict__ rows,
                                              int* __restrict__ counts, int E2,
                                              const float* __restrict__ w1,
                                              const float* __restrict__ w2,
                                              _Float16* __restrict__ w1T,
                                              _Float16* __restrict__ w2T) {
  int e = blockIdx.x * 256 + threadIdx.x;
  if (e < E2) atomicAdd(&counts[rows[e]], 1);
  if (e < 128 * KPAD) {
    int j = e / KPAD, f = e % KPAD;
    w1T[e] = (f < 66) ? (_Float16)w1[f * 128 + j] : (_Float16)0.0f;
  } else if (e < 128 * KPAD + 64 * KPAD) {
    int k = e - 128 * KPAD;
    int j = k / KPAD, f = k % KPAD;
    w2T[k] = (f < 66) ? (_Float16)w2[f * 64 + j] : (_Float16)0.0f;
  }
}

// Single block; counts staged through LDS with coalesced int4 loads.
__global__ __launch_bounds__(256) void scan_k(const int* __restrict__ counts,
                                              int* __restrict__ rowptr,
                                              int* __restrict__ wofs, int n) {
  __shared__ int lbuf[10240];
  __shared__ int sums[256];
  int t = threadIdx.x;
  for (int i = t; i < N_NODES / 4; i += 256)
    reinterpret_cast<int4*>(lbuf)[i] = reinterpret_cast<const int4*>(counts)[i];
  for (int i = N_NODES + t; i < 10240; i += 256) lbuf[i] = 0;
  __syncthreads();
  int base = t * 40;
  int v[40];
  int run = 0;
#pragma unroll
  for (int i = 0; i < 40; ++i) { v[i] = run; run += lbuf[base + i]; }
  sums[t] = run;
  __syncthreads();
  for (int off = 1; off < 256; off <<= 1) {
    int x = (t >= off) ? sums[t - off] : 0;
    __syncthreads();
    sums[t] += x;
    __syncthreads();
  }
  int tbase = (t == 0) ? 0 : sums[t - 1];
#pragma unroll
  for (int i = 0; i < 40; ++i) lbuf[base + i] = tbase + v[i];
  __syncthreads();
  for (int i = t; i < N_NODES / 4; i += 256) {
    int4 w = reinterpret_cast<int4*>(lbuf)[i];
    reinterpret_cast<int4*>(rowptr)[i] = w;
    reinterpret_cast<int4*>(wofs)[i] = w;
  }
  if (t == 255) rowptr[N_NODES] = sums[255];
}

// ecv stores {col*2048 (byte offset), bitcast(val)} pairs.
__global__ __launch_bounds__(256) void scatter_k(const int* __restrict__ rows,
                                                 const int* __restrict__ cols,
                                                 const float* __restrict__ vals,
                                                 int* __restrict__ wofs,
                                                 int2* __restrict__ ecv, int E2) {
  int e = blockIdx.x * 256 + threadIdx.x;
  if (e < E2) {
    int r = rows[e];
    int p = atomicAdd(&wofs[r], 1);
    ecv[p] = make_int2(cols[e] << 11, __float_as_int(vals[e]));
  }
}

// ---------------- feature build (phase 1 only; phase-2 build fused into gcn1) ----------------
__device__ __forceinline__ void pack_row_fp8(const float* T, int n, int t,
                                             unsigned char* xcat8) {
  int k0 = t * 8;
  int f8 = k0 >> 5;
  int b0 = k0 & 31;
  const float* Ts = &T[(f8 + 2) * 33 + b0];
  int d0 = __builtin_amdgcn_cvt_pk_fp8_f32(Ts[0], Ts[1], 0, false);
  d0     = __builtin_amdgcn_cvt_pk_fp8_f32(Ts[2], Ts[3], d0, true);
  int d1 = __builtin_amdgcn_cvt_pk_fp8_f32(Ts[4], Ts[5], 0, false);
  d1     = __builtin_amdgcn_cvt_pk_fp8_f32(Ts[6], Ts[7], d1, true);
  *reinterpret_cast<uint2*>(xcat8 + (size_t)n * XROW + k0) = make_uint2(d0, d1);
}

__global__ __launch_bounds__(256) void build_x1(const float* __restrict__ inputs,
                                                const float* __restrict__ state,
                                                unsigned char* __restrict__ xcat8,
                                                __half2* __restrict__ xin) {
  int n = blockIdx.x, t = threadIdx.x;
  __shared__ float T[66 * 33];
  int f = t & 63, bq = t >> 6;
#pragma unroll
  for (int bb = 0; bb < 8; ++bb) {
    int b = bq + bb * 4;
    T[(f + 2) * 33 + b] = state[(size_t)b * 640000 + (size_t)n * 64 + f];
  }
  if (t < 64) {
    int b0 = t & 31, f0 = t >> 5;
    T[f0 * 33 + b0] = inputs[(size_t)b0 * 20000 + (size_t)n * 2 + f0];
  }
  __syncthreads();
  pack_row_fp8(T, n, t, xcat8);
  if (t < 32) {
    int f0 = t >> 4, b = (t & 15) * 2;
    xin[(size_t)n * 32 + t] = __floats2half2_rn(T[f0 * 33 + b], T[f0 * 33 + b + 1]);
  }
}

// ---------------- yin = M @ X_in ----------------
__global__ __launch_bounds__(256) void yin_k(const int* __restrict__ rowptr,
                                             const int2* __restrict__ ecv,
                                             const __half* __restrict__ xin,
                                             float* __restrict__ yin) {
  int n = blockIdx.x * 32 + (threadIdx.x >> 3);
  int lane = threadIdx.x & 7;
  if (n >= N_NODES) return;
  float acc[8];
#pragma unroll
  for (int i = 0; i < 8; ++i) acc[i] = 0.0f;
  int s = rowptr[n], e = rowptr[n + 1];
  for (int ee = s; ee < e; ++ee) {
    int2 cv = ecv[ee];
    float v = __int_as_float(cv.y);
    const char* p = reinterpret_cast<const char*>(xin) + (size_t)((unsigned)cv.x >> 4);
    uint4 raw = reinterpret_cast<const uint4*>(p)[lane];
    const __half2* h = reinterpret_cast<const __half2*>(&raw);
#pragma unroll
    for (int i = 0; i < 4; ++i) {
      float2 x = __half22float2(h[i]);
      acc[2 * i]     += v * x.x;
      acc[2 * i + 1] += v * x.y;
    }
  }
  float4* dst = reinterpret_cast<float4*>(yin + (size_t)n * 64 + lane * 8);
  dst[0] = make_float4(acc[0], acc[1], acc[2], acc[3]);
  dst[1] = make_float4(acc[4], acc[5], acc[6], acc[7]);
}

// Consume one 8B chunk (8 fp8) into 4 packed-f32 accumulators (v_pk_fma_f32).
__device__ __forceinline__ void consume8f8(uint2 u, float v, v2f* acc) {
  v2f p0 = __builtin_amdgcn_cvt_pk_f32_fp8((int)u.x, false);
  v2f p1 = __builtin_amdgcn_cvt_pk_f32_fp8((int)u.x, true);
  v2f p2 = __builtin_amdgcn_cvt_pk_f32_fp8((int)u.y, false);
  v2f p3 = __builtin_amdgcn_cvt_pk_f32_fp8((int)u.y, true);
  v2f vv = {v, v};
  acc[0] += vv * p0;
  acc[1] += vv * p1;
  acc[2] += vv * p2;
  acc[3] += vv * p3;
}

// Load one group of 8 edges: edge meta via UNIFORM (scalar) loads, gathers issued
// with SADDR-form loads (base uniform, per-thread offset t*8 + scalar col offset).
__device__ __forceinline__ void ld_grp(const int2* __restrict__ ep, int gsz,
                                       const unsigned char* __restrict__ xcat8,
                                       unsigned t8, uint2* r, float* v) {
#pragma unroll
  for (int q = 0; q < 8; ++q) {
    int2 c = ep[q];                       // uniform -> s_load
    if (q >= gsz) { c.x = 0; c.y = 0; }   // masked tail: row 0, weight 0
    unsigned off = (unsigned)c.x + t8;    // 1 VALU add (SGPR + VGPR)
    r[q] = *reinterpret_cast<const uint2*>(xcat8 + off);
    v[q] = __int_as_float(c.y);           // stays scalar
  }
}

__device__ __forceinline__ void cons_grp(const uint2* r, const float* v, v2f* acc) {
#pragma unroll
  for (int q = 0; q < 8; ++q) consume8f8(r[q], v[q], acc);
}

// Shared SpMM body: scalar edge stream, groups of 8, double-buffered (16 loads
// in flight / wave), no LDS edge staging, no barriers in the gather loop.
// Result staged to fp16 accH[b][k]: k=0,1 from yin, k=2..65 state part,
// k=66..95 zero-padded for MFMA.
__device__ __forceinline__ void spmm_body(int n, int t,
                                          const int* __restrict__ rowptr,
                                          const int2* __restrict__ ecv,
                                          const unsigned char* __restrict__ xcat8,
                                          const float* __restrict__ yin,
                                          _Float16* accH) {
  v2f acc[4];
#pragma unroll
  for (int i = 0; i < 4; ++i) acc[i] = (v2f){0.0f, 0.0f};

  unsigned t8 = (unsigned)t * 8u;
  int s = rowptr[n], e = rowptr[n + 1];
  int ne = e - s;
  int ng = (ne + 7) >> 3;
  const int2* ep = ecv + s;

  uint2 rA[8], rB[8];
  float vA[8], vB[8];
  ld_grp(ep, ne, xcat8, t8, rA, vA);
  int g = 1;
  for (; g + 1 < ng; g += 2) {
    ld_grp(ep + 8 * g, ne - 8 * g, xcat8, t8, rB, vB);
    cons_grp(rA, vA, acc);
    ld_grp(ep + 8 * (g + 1), ne - 8 * (g + 1), xcat8, t8, rA, vA);
    cons_grp(rB, vB, acc);
  }
  if (g < ng) {
    ld_grp(ep + 8 * g, ne - 8 * g, xcat8, t8, rB, vB);
    cons_grp(rA, vA, acc);
    cons_grp(rB, vB, acc);
  } else {
    cons_grp(rA, vA, acc);
  }

  // ---- stage into fp16 accH[b][k] ----
  {
    int f8 = t >> 2;
    int b0 = (t & 3) * 8;
    float a[8] = {acc[0].x, acc[0].y, acc[1].x, acc[1].y,
                  acc[2].x, acc[2].y, acc[3].x, acc[3].y};
    _Float16* dst = accH + (f8 + 2);
#pragma unroll
    for (int i = 0; i < 8; ++i) {
      dst[(b0 + i) * ASTR] = (_Float16)a[i];
    }
  }
  if (t < 64) {
    int f = t >> 5, b = t & 31;
    accH[b * ASTR + f] = (_Float16)yin[(size_t)n * 64 + t];
  }
  for (int id = t; id < 32 * 19; id += 256) {
    int b = id / 19, c = id % 19;
    *reinterpret_cast<unsigned int*>(
        reinterpret_cast<char*>(accH) + b * (ASTR * 2) + 132 + c * 4) = 0u;
  }
  __syncthreads();
}

// ---------------- phase 1: SpMM + MFMA GEMM + sigmoid ----------------
// n < 5000 : outputs are r-gates of nodes 2n,2n+1 -> emit fp8 x2 rows (r*state).
// n >= 5000: outputs are u-gates -> write fp16 valu rows (node index n-5000).
__global__ __launch_bounds__(256) void gcn1(const int* __restrict__ rowptr,
                                            const int2* __restrict__ ecv,
                                            const unsigned char* __restrict__ xcat8,
                                            const float* __restrict__ yin,
                                            const _Float16* __restrict__ w1T,
                                            const float* __restrict__ b1,
                                            const float* __restrict__ state,
                                            unsigned char* __restrict__ xcat2,
                                            __half* __restrict__ valu) {
  int n = blockIdx.x, t = threadIdx.x;
  __shared__ _Float16 accH[32 * ASTR];                 // 6656 B
  __shared__ __align__(16) char regionA[32 * 136 * 2]; // 8704 B (vstage)

  spmm_body(n, t, rowptr, ecv, xcat8, yin, accH);

  int wv = t >> 6, l = t & 63;
  int mt = wv & 1, ntb = (wv >> 1) * 4;
  int lr = l & 15, lg = l >> 4;
  const _Float16* aB = accH + (size_t)(mt * 16 + lr) * ASTR + lg * 8;
  half8 afr0 = *reinterpret_cast<const half8*>(aB);
  half8 afr1 = *reinterpret_cast<const half8*>(aB + 32);
  half8 afr2 = *reinterpret_cast<const half8*>(aB + 64);
  _Float16* vstage = reinterpret_cast<_Float16*>(regionA);

#pragma unroll
  for (int tt = 0; tt < 4; ++tt) {
    int j = (ntb + tt) * 16 + lr;
    const _Float16* wB = w1T + (size_t)j * KPAD + lg * 8;
    f32x4 c = {0.0f, 0.0f, 0.0f, 0.0f};
    c = __builtin_amdgcn_mfma_f32_16x16x32_f16(afr0, *reinterpret_cast<const half8*>(wB), c, 0, 0, 0);
    c = __builtin_amdgcn_mfma_f32_16x16x32_f16(afr1, *reinterpret_cast<const half8*>(wB + 32), c, 0, 0, 0);
    c = __builtin_amdgcn_mfma_f32_16x16x32_f16(afr2, *reinterpret_cast<const half8*>(wB + 64), c, 0, 0, 0);
    float bj = b1[j];
#pragma unroll
    for (int i = 0; i < 4; ++i) {
      int b = mt * 16 + lg * 4 + i;
      vstage[b * 136 + j] = (_Float16)sigmoidf(c[i] + bj);
    }
  }
  __syncthreads();

  if (n < 5000) {
    // r-path: xcat2[nn][f*32 + b] = fp8( r(nn,b,f) * state[b][nn][f] ), nn = 2n + (t>>7)
    int nn_i = t >> 7, rem = t & 127;
    int f = rem >> 1, b0 = (rem & 1) * 16;
    int nn = n * 2 + nn_i;
    int jj = nn_i * 64 + f;
    const float* sp = state + (size_t)b0 * 640000 + (size_t)nn * 64 + f;
    const _Float16* vp = vstage + b0 * 136 + jj;
    unsigned int d[4];
#pragma unroll
    for (int q = 0; q < 4; ++q) {
      float x0 = (float)vp[(4 * q + 0) * 136] * sp[(size_t)(4 * q + 0) * 640000];
      float x1 = (float)vp[(4 * q + 1) * 136] * sp[(size_t)(4 * q + 1) * 640000];
      float x2 = (float)vp[(4 * q + 2) * 136] * sp[(size_t)(4 * q + 2) * 640000];
      float x3 = (float)vp[(4 * q + 3) * 136] * sp[(size_t)(4 * q + 3) * 640000];
      int dd = __builtin_amdgcn_cvt_pk_fp8_f32(x0, x1, 0, false);
      dd     = __builtin_amdgcn_cvt_pk_fp8_f32(x2, x3, dd, true);
      d[q] = (unsigned)dd;
    }
    *reinterpret_cast<uint4*>(xcat2 + (size_t)nn * XROW + f * 32 + b0) =
        make_uint4(d[0], d[1], d[2], d[3]);
  } else {
    // u-path: vectorized copy to valu (node index n-5000)
    int b = t >> 3, jg = t & 7;
    const uint4* src = reinterpret_cast<const uint4*>(vstage + b * 136 + jg * 16);
    uint4 q0 = src[0];
    uint4 q1 = src[1];
    __half* vb = valu + (size_t)(n - 5000) * 4096 + b * 128 + jg * 16;
    *reinterpret_cast<uint4*>(vb) = q0;
    *reinterpret_cast<uint4*>(vb + 8) = q1;
  }
}

// ---------------- phase 2: SpMM + MFMA GEMM(96->64) + relu + gate -> out ----------------
__global__ __launch_bounds__(256) void gcn2(const int* __restrict__ rowptr,
                                            const int2* __restrict__ ecv,
                                            const unsigned char* __restrict__ xcat2,
                                            const float* __restrict__ yin,
                                            const _Float16* __restrict__ w2T,
                                            const float* __restrict__ b2,
                                            const __half* __restrict__ valu,
                                            const float* __restrict__ state,
                                            float* __restrict__ out) {
  int n = blockIdx.x, t = threadIdx.x;
  __shared__ _Float16 accH[32 * ASTR];
  __shared__ __align__(16) char regionA[32 * 68 * 4];  // ostage

  spmm_body(n, t, rowptr, ecv, xcat2, yin, accH);

  int wv = t >> 6, l = t & 63;
  int mt = wv & 1, ntb = (wv >> 1) * 2;
  int lr = l & 15, lg = l >> 4;
  const _Float16* aB = accH + (size_t)(mt * 16 + lr) * ASTR + lg * 8;
  half8 afr0 = *reinterpret_cast<const half8*>(aB);
  half8 afr1 = *reinterpret_cast<const half8*>(aB + 32);
  half8 afr2 = *reinterpret_cast<const half8*>(aB + 64);
  float* ostage = reinterpret_cast<float*>(regionA);   // [32][68]

#pragma unroll
  for (int tt = 0; tt < 2; ++tt) {
    int j = (ntb + tt) * 16 + lr;
    const _Float16* wB = w2T + (size_t)j * KPAD + lg * 8;
    f32x4 c = {0.0f, 0.0f, 0.0f, 0.0f};
    c = __builtin_amdgcn_mfma_f32_16x16x32_f16(afr0, *reinterpret_cast<const half8*>(wB), c, 0, 0, 0);
    c = __builtin_amdgcn_mfma_f32_16x16x32_f16(afr1, *reinterpret_cast<const half8*>(wB + 32), c, 0, 0, 0);
    c = __builtin_amdgcn_mfma_f32_16x16x32_f16(afr2, *reinterpret_cast<const half8*>(wB + 64), c, 0, 0, 0);
    float bj = b2[j];
#pragma unroll
    for (int i = 0; i < 4; ++i) {
      int b = mt * 16 + lg * 4 + i;
      ostage[b * 68 + j] = fmaxf(c[i] + bj, 0.0f);
    }
  }
  __syncthreads();

  int bg = t >> 4, jg = t & 15;
  int n2 = n >> 1, no = n & 1;
  const __half* up = valu + (size_t)n2 * 4096 + (size_t)no * 64 + jg * 4;
#pragma unroll
  for (int i = 0; i < 2; ++i) {
    int b = bg * 2 + i;
    size_t idx = (size_t)b * 640000 + (size_t)n * 64 + jg * 4;
    float4 sv = *reinterpret_cast<const float4*>(state + idx);
    float4 cc = *reinterpret_cast<const float4*>(ostage + b * 68 + jg * 4);
    union { uint2 u; __half2 h[2]; } pk;
    pk.u = *reinterpret_cast<const uint2*>(up + (size_t)b * 128);
    float2 u01 = __half22float2(pk.h[0]);
    float2 u23 = __half22float2(pk.h[1]);
    float4 h;
    h.x = u01.x * sv.x + (1.0f - u01.x) * cc.x;
    h.y = u01.y * sv.y + (1.0f - u01.y) * cc.y;
    h.z = u23.x * sv.z + (1.0f - u23.x) * cc.z;
    h.w = u23.y * sv.w + (1.0f - u23.y) * cc.w;
    *reinterpret_cast<float4*>(out + idx) = h;
  }
}

// ---------------- host ----------------
static inline size_t alignup(size_t x) { return (x + 255) & ~(size_t)255; }

extern "C" void kernel_launch(void* const* d_in, const int* in_sizes, int n_in,
                              void* d_out, int out_size, void* d_ws, size_t ws_size,
                              hipStream_t stream) {
  const float* inputs = (const float*)d_in[0];
  const float* state  = (const float*)d_in[1];
  const int*   m_rows = (const int*)d_in[2];
  const int*   m_cols = (const int*)d_in[3];
  const float* m_vals = (const float*)d_in[4];
  const float* w1     = (const float*)d_in[5];
  const float* b1     = (const float*)d_in[6];
  const float* w2     = (const float*)d_in[7];
  const float* b2     = (const float*)d_in[8];
  float* out = (float*)d_out;

  const int N  = N_NODES;
  const int E2 = in_sizes[2];

  char* ws = (char*)d_ws;
  size_t off = 0;
  int* counts = (int*)(ws + off); off = alignup(off + (size_t)N * 4);
  int* rowptr = (int*)(ws + off); off = alignup(off + (size_t)(N + 1) * 4);
  int* wofs   = (int*)(ws + off); off = alignup(off + (size_t)N * 4);
  int2* ecv   = (int2*)(ws + off); off = alignup(off + (size_t)E2 * 8 + 64); // +64B over-read slack
  unsigned char* xcat8 = (unsigned char*)(ws + off); off = alignup(off + (size_t)N * XROW);
  unsigned char* xcat2 = (unsigned char*)(ws + off); off = alignup(off + (size_t)N * XROW);
  __half* valu = (__half*)(ws + off); off = alignup(off + (size_t)5000 * 4096 * 2);
  float* yin  = (float*)(ws + off); off = alignup(off + (size_t)N * 64 * 4);
  __half* xin = (__half*)(ws + off); off = alignup(off + (size_t)N * 64 * 2);
  _Float16* w1T = (_Float16*)(ws + off); off = alignup(off + (size_t)128 * KPAD * 2);
  _Float16* w2T = (_Float16*)(ws + off); off = alignup(off + (size_t)64 * KPAD * 2);
  if (off > ws_size) { return; }

  hipMemsetAsync(counts, 0, (size_t)N * 4, stream);

  int eb = (E2 + 255) / 256;
  hipLaunchKernelGGL(hist_k,    dim3(eb), dim3(256), 0, stream, m_rows, counts, E2,
                     w1, w2, w1T, w2T);
  hipLaunchKernelGGL(scan_k,    dim3(1),  dim3(256), 0, stream, counts, rowptr, wofs, N);
  hipLaunchKernelGGL(scatter_k, dim3(eb), dim3(256), 0, stream, m_rows, m_cols, m_vals,
                     wofs, ecv, E2);
  hipLaunchKernelGGL(build_x1,  dim3(N),  dim3(256), 0, stream, inputs, state, xcat8,
                     (__half2*)xin);
  hipLaunchKernelGGL(yin_k,     dim3((N + 31) / 32), dim3(256), 0, stream,
                     rowptr, ecv, xin, yin);
  hipLaunchKernelGGL(gcn1,      dim3(N),  dim3(256), 0, stream, rowptr, ecv,
                     xcat8, yin, w1T, b1, state, xcat2, valu);
  hipLaunchKernelGGL(gcn2,      dim3(N),  dim3(256), 0, stream, rowptr, ecv,
                     xcat2, yin, w2T, b2, valu, state, out);
}

// Round 4
// 437.551 us; speedup vs baseline: 1.2275x; 1.0031x over previous
//
#include <hip/hip_runtime.h>
#include <hip/hip_fp16.h>
#include <cstdint>
#include <cstdio>

#define N_NODES 10000
#define BATCH   32
#define UNITS   64
#define F_DIM   66            // 2 + 64
#define XROW    2048          // fp8 state-part row bytes (64 f * 32 b)
#define KPAD    96            // MFMA K padded (3 x 32)
#define ASTR    104           // accH row stride in halves (96 + 8 pad)
#define GRP     10            // gather group size (2 groups in flight = 20 loads/wave)

typedef float v2f __attribute__((ext_vector_type(2)));
typedef float f32x4 __attribute__((ext_vector_type(4)));
typedef _Float16 half8 __attribute__((ext_vector_type(8)));

__device__ __forceinline__ float sigmoidf(float x) {
  return 1.0f / (1.0f + __expf(-x));
}

// ---------------- CSR build (+ weight prep folded in) ----------------
__global__ __launch_bounds__(256) void hist_k(const int* __restrict__ rows,
                                              int* __restrict__ counts, int E2,
                                              const float* __restrict__ w1,
                                              const float* __restrict__ w2,
                                              _Float16* __restrict__ w1T,
                                              _Float16* __restrict__ w2T) {
  int e = blockIdx.x * 256 + threadIdx.x;
  if (e < E2) atomicAdd(&counts[rows[e]], 1);
  if (e < 128 * KPAD) {
    int j = e / KPAD, f = e % KPAD;
    w1T[e] = (f < 66) ? (_Float16)w1[f * 128 + j] : (_Float16)0.0f;
  } else if (e < 128 * KPAD + 64 * KPAD) {
    int k = e - 128 * KPAD;
    int j = k / KPAD, f = k % KPAD;
    w2T[k] = (f < 66) ? (_Float16)w2[f * 64 + j] : (_Float16)0.0f;
  }
}

// Single block; counts staged through LDS with coalesced int4 loads.
__global__ __launch_bounds__(256) void scan_k(const int* __restrict__ counts,
                                              int* __restrict__ rowptr,
                                              int* __restrict__ wofs, int n) {
  __shared__ int lbuf[10240];
  __shared__ int sums[256];
  int t = threadIdx.x;
  for (int i = t; i < N_NODES / 4; i += 256)
    reinterpret_cast<int4*>(lbuf)[i] = reinterpret_cast<const int4*>(counts)[i];
  for (int i = N_NODES + t; i < 10240; i += 256) lbuf[i] = 0;
  __syncthreads();
  int base = t * 40;
  int v[40];
  int run = 0;
#pragma unroll
  for (int i = 0; i < 40; ++i) { v[i] = run; run += lbuf[base + i]; }
  sums[t] = run;
  __syncthreads();
  for (int off = 1; off < 256; off <<= 1) {
    int x = (t >= off) ? sums[t - off] : 0;
    __syncthreads();
    sums[t] += x;
    __syncthreads();
  }
  int tbase = (t == 0) ? 0 : sums[t - 1];
#pragma unroll
  for (int i = 0; i < 40; ++i) lbuf[base + i] = tbase + v[i];
  __syncthreads();
  for (int i = t; i < N_NODES / 4; i += 256) {
    int4 w = reinterpret_cast<int4*>(lbuf)[i];
    reinterpret_cast<int4*>(rowptr)[i] = w;
    reinterpret_cast<int4*>(wofs)[i] = w;
  }
  if (t == 255) rowptr[N_NODES] = sums[255];
}

// ---------------- fused scatter + phase-1 feature build ----------------
__device__ __forceinline__ void pack_row_fp8(const float* T, int n, int t,
                                             unsigned char* xcat8) {
  int k0 = t * 8;
  int f8 = k0 >> 5;
  int b0 = k0 & 31;
  const float* Ts = &T[(f8 + 2) * 33 + b0];
  int d0 = __builtin_amdgcn_cvt_pk_fp8_f32(Ts[0], Ts[1], 0, false);
  d0     = __builtin_amdgcn_cvt_pk_fp8_f32(Ts[2], Ts[3], d0, true);
  int d1 = __builtin_amdgcn_cvt_pk_fp8_f32(Ts[4], Ts[5], 0, false);
  d1     = __builtin_amdgcn_cvt_pk_fp8_f32(Ts[6], Ts[7], d1, true);
  *reinterpret_cast<uint2*>(xcat8 + (size_t)n * XROW + k0) = make_uint2(d0, d1);
}

// blocks [0, N_NODES): build xcat8 + xin for node n = blockIdx.x
// blocks [N_NODES, ...): scatter edges into ecv = {col*2048, bitcast(val)}
__global__ __launch_bounds__(256) void scat_build(const int* __restrict__ rows,
                                                  const int* __restrict__ cols,
                                                  const float* __restrict__ vals,
                                                  int* __restrict__ wofs,
                                                  int2* __restrict__ ecv, int E2,
                                                  const float* __restrict__ inputs,
                                                  const float* __restrict__ state,
                                                  unsigned char* __restrict__ xcat8,
                                                  __half2* __restrict__ xin) {
  int blk = blockIdx.x, t = threadIdx.x;
  if (blk >= N_NODES) {
    int e = (blk - N_NODES) * 256 + t;
    if (e < E2) {
      int r = rows[e];
      int p = atomicAdd(&wofs[r], 1);
      ecv[p] = make_int2(cols[e] << 11, __float_as_int(vals[e]));
    }
    return;
  }
  int n = blk;
  __shared__ float T[66 * 33];
  int f = t & 63, bq = t >> 6;
#pragma unroll
  for (int bb = 0; bb < 8; ++bb) {
    int b = bq + bb * 4;
    T[(f + 2) * 33 + b] = state[(size_t)b * 640000 + (size_t)n * 64 + f];
  }
  if (t < 64) {
    int b0 = t & 31, f0 = t >> 5;
    T[f0 * 33 + b0] = inputs[(size_t)b0 * 20000 + (size_t)n * 2 + f0];
  }
  __syncthreads();
  pack_row_fp8(T, n, t, xcat8);
  if (t < 32) {
    int f0 = t >> 4, b = (t & 15) * 2;
    xin[(size_t)n * 32 + t] = __floats2half2_rn(T[f0 * 33 + b], T[f0 * 33 + b + 1]);
  }
}

// ---------------- yin = M @ X_in ----------------
__global__ __launch_bounds__(256) void yin_k(const int* __restrict__ rowptr,
                                             const int2* __restrict__ ecv,
                                             const __half* __restrict__ xin,
                                             float* __restrict__ yin) {
  int n = blockIdx.x * 32 + (threadIdx.x >> 3);
  int lane = threadIdx.x & 7;
  if (n >= N_NODES) return;
  float acc[8];
#pragma unroll
  for (int i = 0; i < 8; ++i) acc[i] = 0.0f;
  int s = rowptr[n], e = rowptr[n + 1];
  for (int ee = s; ee < e; ++ee) {
    int2 cv = ecv[ee];
    float v = __int_as_float(cv.y);
    const char* p = reinterpret_cast<const char*>(xin) + (size_t)((unsigned)cv.x >> 4);
    uint4 raw = reinterpret_cast<const uint4*>(p)[lane];
    const __half2* h = reinterpret_cast<const __half2*>(&raw);
#pragma unroll
    for (int i = 0; i < 4; ++i) {
      float2 x = __half22float2(h[i]);
      acc[2 * i]     += v * x.x;
      acc[2 * i + 1] += v * x.y;
    }
  }
  float4* dst = reinterpret_cast<float4*>(yin + (size_t)n * 64 + lane * 8);
  dst[0] = make_float4(acc[0], acc[1], acc[2], acc[3]);
  dst[1] = make_float4(acc[4], acc[5], acc[6], acc[7]);
}

// Consume one 8B chunk (8 fp8) into 4 packed-f32 accumulators (v_pk_fma_f32).
__device__ __forceinline__ void consume8f8(uint2 u, float v, v2f* acc) {
  v2f p0 = __builtin_amdgcn_cvt_pk_f32_fp8((int)u.x, false);
  v2f p1 = __builtin_amdgcn_cvt_pk_f32_fp8((int)u.x, true);
  v2f p2 = __builtin_amdgcn_cvt_pk_f32_fp8((int)u.y, false);
  v2f p3 = __builtin_amdgcn_cvt_pk_f32_fp8((int)u.y, true);
  v2f vv = {v, v};
  acc[0] += vv * p0;
  acc[1] += vv * p1;
  acc[2] += vv * p2;
  acc[3] += vv * p3;
}

// Load one group of GRP edges: edge meta via UNIFORM (scalar) loads, gathers
// issued as SADDR-form loads (uniform base + per-thread offset).
__device__ __forceinline__ void ld_grp(const int2* __restrict__ ep, int gsz,
                                       const unsigned char* __restrict__ xcat8,
                                       unsigned t8, uint2* r, float* v) {
#pragma unroll
  for (int q = 0; q < GRP; ++q) {
    int2 c = ep[q];                       // uniform -> s_load
    if (q >= gsz) { c.x = 0; c.y = 0; }   // masked tail: row 0, weight 0 (scalar ops)
    unsigned off = (unsigned)c.x + t8;    // 1 VALU add (SGPR + VGPR)
    r[q] = *reinterpret_cast<const uint2*>(xcat8 + off);
    v[q] = __int_as_float(c.y);           // stays scalar
  }
}

__device__ __forceinline__ void cons_grp(const uint2* r, const float* v, v2f* acc) {
#pragma unroll
  for (int q = 0; q < GRP; ++q) consume8f8(r[q], v[q], acc);
}

// Shared SpMM body: scalar edge stream, groups of GRP, double-buffered
// (2*GRP loads in flight / wave), no LDS edge staging, no barriers.
// Result staged to fp16 accH[b][k]: k=0,1 from yin, k=2..65 state part,
// k=66..95 zero-padded for MFMA.
__device__ __forceinline__ void spmm_body(int n, int t,
                                          const int* __restrict__ rowptr,
                                          const int2* __restrict__ ecv,
                                          const unsigned char* __restrict__ xcat8,
                                          const float* __restrict__ yin,
                                          _Float16* accH) {
  v2f acc[4];
#pragma unroll
  for (int i = 0; i < 4; ++i) acc[i] = (v2f){0.0f, 0.0f};

  unsigned t8 = (unsigned)t * 8u;
  int s = rowptr[n], e = rowptr[n + 1];
  int ne = e - s;
  int ng = (ne + GRP - 1) / GRP;
  const int2* ep = ecv + s;

  uint2 rA[GRP], rB[GRP];
  float vA[GRP], vB[GRP];
  ld_grp(ep, ne, xcat8, t8, rA, vA);
  int g = 1;
  for (; g + 1 < ng; g += 2) {
    ld_grp(ep + GRP * g, ne - GRP * g, xcat8, t8, rB, vB);
    cons_grp(rA, vA, acc);
    ld_grp(ep + GRP * (g + 1), ne - GRP * (g + 1), xcat8, t8, rA, vA);
    cons_grp(rB, vB, acc);
  }
  if (g < ng) {
    ld_grp(ep + GRP * g, ne - GRP * g, xcat8, t8, rB, vB);
    cons_grp(rA, vA, acc);
    cons_grp(rB, vB, acc);
  } else {
    cons_grp(rA, vA, acc);
  }

  // ---- stage into fp16 accH[b][k] ----
  {
    int f8 = t >> 2;
    int b0 = (t & 3) * 8;
    float a[8] = {acc[0].x, acc[0].y, acc[1].x, acc[1].y,
                  acc[2].x, acc[2].y, acc[3].x, acc[3].y};
    _Float16* dst = accH + (f8 + 2);
#pragma unroll
    for (int i = 0; i < 8; ++i) {
      dst[(b0 + i) * ASTR] = (_Float16)a[i];
    }
  }
  if (t < 64) {
    int f = t >> 5, b = t & 31;
    accH[b * ASTR + f] = (_Float16)yin[(size_t)n * 64 + t];
  }
  for (int id = t; id < 32 * 19; id += 256) {
    int b = id / 19, c = id % 19;
    *reinterpret_cast<unsigned int*>(
        reinterpret_cast<char*>(accH) + b * (ASTR * 2) + 132 + c * 4) = 0u;
  }
  __syncthreads();
}

// ---------------- phase 1: SpMM + MFMA GEMM + sigmoid ----------------
// n < 5000 : outputs are r-gates of nodes 2n,2n+1 -> emit fp8 x2 rows (r*state).
// n >= 5000: outputs are u-gates -> write fp16 valu rows (node index n-5000).
__global__ __launch_bounds__(256) void gcn1(const int* __restrict__ rowptr,
                                            const int2* __restrict__ ecv,
                                            const unsigned char* __restrict__ xcat8,
                                            const float* __restrict__ yin,
                                            const _Float16* __restrict__ w1T,
                                            const float* __restrict__ b1,
                                            const float* __restrict__ state,
                                            unsigned char* __restrict__ xcat2,
                                            __half* __restrict__ valu) {
  int n = blockIdx.x, t = threadIdx.x;
  __shared__ _Float16 accH[32 * ASTR];                 // 6656 B
  __shared__ __align__(16) char regionA[32 * 136 * 2]; // 8704 B (vstage)

  spmm_body(n, t, rowptr, ecv, xcat8, yin, accH);

  int wv = t >> 6, l = t & 63;
  int mt = wv & 1, ntb = (wv >> 1) * 4;
  int lr = l & 15, lg = l >> 4;
  const _Float16* aB = accH + (size_t)(mt * 16 + lr) * ASTR + lg * 8;
  half8 afr0 = *reinterpret_cast<const half8*>(aB);
  half8 afr1 = *reinterpret_cast<const half8*>(aB + 32);
  half8 afr2 = *reinterpret_cast<const half8*>(aB + 64);
  _Float16* vstage = reinterpret_cast<_Float16*>(regionA);

#pragma unroll
  for (int tt = 0; tt < 4; ++tt) {
    int j = (ntb + tt) * 16 + lr;
    const _Float16* wB = w1T + (size_t)j * KPAD + lg * 8;
    f32x4 c = {0.0f, 0.0f, 0.0f, 0.0f};
    c = __builtin_amdgcn_mfma_f32_16x16x32_f16(afr0, *reinterpret_cast<const half8*>(wB), c, 0, 0, 0);
    c = __builtin_amdgcn_mfma_f32_16x16x32_f16(afr1, *reinterpret_cast<const half8*>(wB + 32), c, 0, 0, 0);
    c = __builtin_amdgcn_mfma_f32_16x16x32_f16(afr2, *reinterpret_cast<const half8*>(wB + 64), c, 0, 0, 0);
    float bj = b1[j];
#pragma unroll
    for (int i = 0; i < 4; ++i) {
      int b = mt * 16 + lg * 4 + i;
      vstage[b * 136 + j] = (_Float16)sigmoidf(c[i] + bj);
    }
  }
  __syncthreads();

  if (n < 5000) {
    // r-path, coalesced mapping: f = t&63 so state reads are 256B/wave.
    // thread: nn_i = t>>7, bg = (t>>6)&1 -> 16 consecutive b = bg*16 + q*4 + i.
    int nn_i = t >> 7;
    int f    = t & 63;
    int bg   = (t >> 6) & 1;
    int nn = n * 2 + nn_i;
    int jj = nn_i * 64 + f;
    const float* sp = state + (size_t)nn * 64 + f;
    const _Float16* vp = vstage + jj;
    int bbase = bg * 16;
    unsigned int d[4];
#pragma unroll
    for (int q = 0; q < 4; ++q) {
      int b0 = bbase + q * 4;
      float x0 = (float)vp[(b0 + 0) * 136] * sp[(size_t)(b0 + 0) * 640000];
      float x1 = (float)vp[(b0 + 1) * 136] * sp[(size_t)(b0 + 1) * 640000];
      float x2 = (float)vp[(b0 + 2) * 136] * sp[(size_t)(b0 + 2) * 640000];
      float x3 = (float)vp[(b0 + 3) * 136] * sp[(size_t)(b0 + 3) * 640000];
      int dd = __builtin_amdgcn_cvt_pk_fp8_f32(x0, x1, 0, false);
      dd     = __builtin_amdgcn_cvt_pk_fp8_f32(x2, x3, dd, true);
      d[q] = (unsigned)dd;
    }
    *reinterpret_cast<uint4*>(xcat2 + (size_t)nn * XROW + f * 32 + bbase) =
        make_uint4(d[0], d[1], d[2], d[3]);
  } else {
    // u-path: vectorized copy to valu (node index n-5000)
    int b = t >> 3, jg = t & 7;
    const uint4* src = reinterpret_cast<const uint4*>(vstage + b * 136 + jg * 16);
    uint4 q0 = src[0];
    uint4 q1 = src[1];
    __half* vb = valu + (size_t)(n - 5000) * 4096 + b * 128 + jg * 16;
    *reinterpret_cast<uint4*>(vb) = q0;
    *reinterpret_cast<uint4*>(vb + 8) = q1;
  }
}

// ---------------- phase 2: SpMM + MFMA GEMM(96->64) + relu + gate -> out ----------------
__global__ __launch_bounds__(256) void gcn2(const int* __restrict__ rowptr,
                                            const int2* __restrict__ ecv,
                                            const unsigned char* __restrict__ xcat2,
                                            const float* __restrict__ yin,
                                            const _Float16* __restrict__ w2T,
                                            const float* __restrict__ b2,
                                            const __half* __restrict__ valu,
                                            const float* __restrict__ state,
                                            float* __restrict__ out) {
  int n = blockIdx.x, t = threadIdx.x;
  __shared__ _Float16 accH[32 * ASTR];
  __shared__ __align__(16) char regionA[32 * 68 * 4];  // ostage

  spmm_body(n, t, rowptr, ecv, xcat2, yin, accH);

  int wv = t >> 6, l = t & 63;
  int mt = wv & 1, ntb = (wv >> 1) * 2;
  int lr = l & 15, lg = l >> 4;
  const _Float16* aB = accH + (size_t)(mt * 16 + lr) * ASTR + lg * 8;
  half8 afr0 = *reinterpret_cast<const half8*>(aB);
  half8 afr1 = *reinterpret_cast<const half8*>(aB + 32);
  half8 afr2 = *reinterpret_cast<const half8*>(aB + 64);
  float* ostage = reinterpret_cast<float*>(regionA);   // [32][68]

#pragma unroll
  for (int tt = 0; tt < 2; ++tt) {
    int j = (ntb + tt) * 16 + lr;
    const _Float16* wB = w2T + (size_t)j * KPAD + lg * 8;
    f32x4 c = {0.0f, 0.0f, 0.0f, 0.0f};
    c = __builtin_amdgcn_mfma_f32_16x16x32_f16(afr0, *reinterpret_cast<const half8*>(wB), c, 0, 0, 0);
    c = __builtin_amdgcn_mfma_f32_16x16x32_f16(afr1, *reinterpret_cast<const half8*>(wB + 32), c, 0, 0, 0);
    c = __builtin_amdgcn_mfma_f32_16x16x32_f16(afr2, *reinterpret_cast<const half8*>(wB + 64), c, 0, 0, 0);
    float bj = b2[j];
#pragma unroll
    for (int i = 0; i < 4; ++i) {
      int b = mt * 16 + lg * 4 + i;
      ostage[b * 68 + j] = fmaxf(c[i] + bj, 0.0f);
    }
  }
  __syncthreads();

  int bg = t >> 4, jg = t & 15;
  int n2 = n >> 1, no = n & 1;
  const __half* up = valu + (size_t)n2 * 4096 + (size_t)no * 64 + jg * 4;
#pragma unroll
  for (int i = 0; i < 2; ++i) {
    int b = bg * 2 + i;
    size_t idx = (size_t)b * 640000 + (size_t)n * 64 + jg * 4;
    float4 sv = *reinterpret_cast<const float4*>(state + idx);
    float4 cc = *reinterpret_cast<const float4*>(ostage + b * 68 + jg * 4);
    union { uint2 u; __half2 h[2]; } pk;
    pk.u = *reinterpret_cast<const uint2*>(up + (size_t)b * 128);
    float2 u01 = __half22float2(pk.h[0]);
    float2 u23 = __half22float2(pk.h[1]);
    float4 h;
    h.x = u01.x * sv.x + (1.0f - u01.x) * cc.x;
    h.y = u01.y * sv.y + (1.0f - u01.y) * cc.y;
    h.z = u23.x * sv.z + (1.0f - u23.x) * cc.z;
    h.w = u23.y * sv.w + (1.0f - u23.y) * cc.w;
    *reinterpret_cast<float4*>(out + idx) = h;
  }
}

// ---------------- host ----------------
static inline size_t alignup(size_t x) { return (x + 255) & ~(size_t)255; }

extern "C" void kernel_launch(void* const* d_in, const int* in_sizes, int n_in,
                              void* d_out, int out_size, void* d_ws, size_t ws_size,
                              hipStream_t stream) {
  const float* inputs = (const float*)d_in[0];
  const float* state  = (const float*)d_in[1];
  const int*   m_rows = (const int*)d_in[2];
  const int*   m_cols = (const int*)d_in[3];
  const float* m_vals = (const float*)d_in[4];
  const float* w1     = (const float*)d_in[5];
  const float* b1     = (const float*)d_in[6];
  const float* w2     = (const float*)d_in[7];
  const float* b2     = (const float*)d_in[8];
  float* out = (float*)d_out;

  const int N  = N_NODES;
  const int E2 = in_sizes[2];

  char* ws = (char*)d_ws;
  size_t off = 0;
  int* counts = (int*)(ws + off); off = alignup(off + (size_t)N * 4);
  int* rowptr = (int*)(ws + off); off = alignup(off + (size_t)(N + 1) * 4);
  int* wofs   = (int*)(ws + off); off = alignup(off + (size_t)N * 4);
  int2* ecv   = (int2*)(ws + off); off = alignup(off + (size_t)E2 * 8 + 256); // +slack for group over-read
  unsigned char* xcat8 = (unsigned char*)(ws + off); off = alignup(off + (size_t)N * XROW);
  unsigned char* xcat2 = (unsigned char*)(ws + off); off = alignup(off + (size_t)N * XROW);
  __half* valu = (__half*)(ws + off); off = alignup(off + (size_t)5000 * 4096 * 2);
  float* yin  = (float*)(ws + off); off = alignup(off + (size_t)N * 64 * 4);
  __half* xin = (__half*)(ws + off); off = alignup(off + (size_t)N * 64 * 2);
  _Float16* w1T = (_Float16*)(ws + off); off = alignup(off + (size_t)128 * KPAD * 2);
  _Float16* w2T = (_Float16*)(ws + off); off = alignup(off + (size_t)64 * KPAD * 2);
  if (off > ws_size) { return; }

  hipMemsetAsync(counts, 0, (size_t)N * 4, stream);

  int eb = (E2 + 255) / 256;
  hipLaunchKernelGGL(hist_k,     dim3(eb), dim3(256), 0, stream, m_rows, counts, E2,
                     w1, w2, w1T, w2T);
  hipLaunchKernelGGL(scan_k,     dim3(1),  dim3(256), 0, stream, counts, rowptr, wofs, N);
  hipLaunchKernelGGL(scat_build, dim3(N + eb), dim3(256), 0, stream,
                     m_rows, m_cols, m_vals, wofs, ecv, E2,
                     inputs, state, xcat8, (__half2*)xin);
  hipLaunchKernelGGL(yin_k,      dim3((N + 31) / 32), dim3(256), 0, stream,
                     rowptr, ecv, xin, yin);
  hipLaunchKernelGGL(gcn1,       dim3(N),  dim3(256), 0, stream, rowptr, ecv,
                     xcat8, yin, w1T, b1, state, xcat2, valu);
  hipLaunchKernelGGL(gcn2,       dim3(N),  dim3(256), 0, stream, rowptr, ecv,
                     xcat2, yin, w2T, b2, valu, state, out);
}